// Round 3
// baseline (1523.911 us; speedup 1.0000x reference)
//
#include <hip/hip_runtime.h>
#include <math.h>

#define BB 16
#define NN 512
#define HH 128
#define EE 4
#define NSTEPS 5
#define ROWS (BB*NN)      // 8192
#define KDIM (NN*EE)      // 2048

typedef _Float16 f16x8 __attribute__((ext_vector_type(8)));
typedef float f32x4 __attribute__((ext_vector_type(4)));

#define MFMA(a,b,c) __builtin_amdgcn_mfma_f32_16x16x32_f16(a, b, c, 0, 0, 0)

__device__ inline void split8(const float* __restrict__ p, f16x8& hi, f16x8& lo) {
    const float4 u = *(const float4*)p;
    const float4 v = *(const float4*)(p + 4);
    float f[8] = {u.x, u.y, u.z, u.w, v.x, v.y, v.z, v.w};
    #pragma unroll
    for (int i = 0; i < 8; i++) {
        _Float16 h = (_Float16)f[i];
        hi[i] = h;
        lo[i] = (_Float16)(f[i] - (float)h);
    }
}

__device__ inline void split1(float v, _Float16* __restrict__ hp, _Float16* __restrict__ lp) {
    _Float16 h = (_Float16)v;
    *hp = h;
    *lp = (_Float16)(v - (float)h);
}

// ---------------------------------------------------------------------------
// Prep: split-fp16 transposed weights + split of initial h = x.
//  WpT[c][k]  (1024x128): c = io*512+e*128+hh -> W_io[k][hh*4+e]; bp[c] fp32.
//  Wzrt[c][k] (384x384):  c<128: W_z[k][c]; c<256: W_r[k][c-128];
//                         else: k<256 ? W_t[k][c-256] : 0.
//  Wt1[c][k]  (128x128):  W_t[256+k][c].
// ---------------------------------------------------------------------------
__global__ void prep_kernel(const float* __restrict__ x,
                            const float* __restrict__ W_in, const float* __restrict__ b_in,
                            const float* __restrict__ W_out, const float* __restrict__ b_out,
                            const float* __restrict__ W_z, const float* __restrict__ W_r,
                            const float* __restrict__ W_t,
                            _Float16* __restrict__ WpTh, _Float16* __restrict__ WpTl,
                            float* __restrict__ bp,
                            _Float16* __restrict__ WzrtH, _Float16* __restrict__ WzrtL,
                            _Float16* __restrict__ Wt1h, _Float16* __restrict__ Wt1l,
                            _Float16* __restrict__ hHi, _Float16* __restrict__ hLo) {
    int idx = blockIdx.x * 256 + threadIdx.x;
    if (idx < 131072) {                                  // WpT
        int c = idx >> 7, k = idx & 127;
        int io = c >> 9, cc = c & 511, e = cc >> 7, hh = cc & 127;
        const float* W = io ? W_out : W_in;
        split1(W[k * 512 + hh * 4 + e], WpTh + idx, WpTl + idx);
        if (k == 0) bp[c] = (io ? b_out : b_in)[hh * 4 + e];
    } else if (idx < 131072 + 147456) {                  // Wzrt
        int j = idx - 131072;
        int c = j / 384, k = j - c * 384;
        float v;
        if (c < 128)      v = W_z[k * 128 + c];
        else if (c < 256) v = W_r[k * 128 + (c - 128)];
        else              v = (k < 256) ? W_t[k * 128 + (c - 256)] : 0.0f;
        split1(v, WzrtH + j, WzrtL + j);
    } else if (idx < 131072 + 147456 + 16384) {          // Wt1
        int j = idx - 131072 - 147456;
        int c = j >> 7, k = j & 127;
        split1(W_t[(256 + k) * 128 + c], Wt1h + j, Wt1l + j);
    } else if (idx < 131072 + 147456 + 16384 + 1048576) { // split x -> h hi/lo
        int j = idx - 131072 - 147456 - 16384;
        split1(x[j], hHi + j, hLo + j);
    }
}

// ---------------------------------------------------------------------------
// YpT[b][c][n'] = sum_k WpT[c][k] * h[b*512+n'][k] + bp[c], split-fp16 out.
// Grid (16,4,16); block 64c x 128n, 4 waves (wave 32c x 64n).
// ---------------------------------------------------------------------------
__global__ __launch_bounds__(256) void xw_mfma(
        const _Float16* __restrict__ hHi, const _Float16* __restrict__ hLo,
        const _Float16* __restrict__ WpTh, const _Float16* __restrict__ WpTl,
        const float* __restrict__ bp,
        _Float16* __restrict__ YpTh, _Float16* __restrict__ YpTl) {
    const int tid = threadIdx.x;
    const int c0 = blockIdx.x * 64;
    const int n0 = blockIdx.y * 128;
    const int b  = blockIdx.z;
    const int w = tid >> 6, l = tid & 63;
    const int lm = l & 15, q = l >> 4;
    const int wr = (w & 1) * 32, wc = (w >> 1) * 64;
    f32x4 zero = {0.f, 0.f, 0.f, 0.f};
    f32x4 acc[2][4];
    #pragma unroll
    for (int i = 0; i < 2; i++)
        #pragma unroll
        for (int j = 0; j < 4; j++) acc[i][j] = zero;
    const size_t aoff = (size_t)(c0 + wr + lm) * 128 + q * 8;
    const size_t boff = (size_t)(b * 512 + n0 + wc + lm) * 128 + q * 8;
    #pragma unroll
    for (int ki = 0; ki < 4; ki++) {
        const int kc = ki * 32;
        f16x8 a0h = *(const f16x8*)(WpTh + aoff + kc);
        f16x8 a0l = *(const f16x8*)(WpTl + aoff + kc);
        f16x8 a1h = *(const f16x8*)(WpTh + aoff + 16 * 128 + kc);
        f16x8 a1l = *(const f16x8*)(WpTl + aoff + 16 * 128 + kc);
        #pragma unroll
        for (int ct = 0; ct < 4; ct++) {
            f16x8 bh = *(const f16x8*)(hHi + boff + (size_t)(ct * 16) * 128 + kc);
            f16x8 bl = *(const f16x8*)(hLo + boff + (size_t)(ct * 16) * 128 + kc);
            acc[0][ct] = MFMA(a0h, bh, acc[0][ct]);
            acc[0][ct] = MFMA(a0h, bl, acc[0][ct]);
            acc[0][ct] = MFMA(a0l, bh, acc[0][ct]);
            acc[1][ct] = MFMA(a1h, bh, acc[1][ct]);
            acc[1][ct] = MFMA(a1h, bl, acc[1][ct]);
            acc[1][ct] = MFMA(a1l, bh, acc[1][ct]);
        }
    }
    #pragma unroll
    for (int rg = 0; rg < 2; rg++)
        #pragma unroll
        for (int rr = 0; rr < 4; rr++) {
            int c = c0 + wr + rg * 16 + q * 4 + rr;
            float bias = bp[c];
            size_t d = ((size_t)b * 1024 + c) * 512 + n0 + wc + lm;
            #pragma unroll
            for (int ct = 0; ct < 4; ct++) {
                float v = acc[rg][ct][rr] + bias;
                split1(v, YpTh + d + ct * 16, YpTl + d + ct * 16);
            }
        }
}

// ---------------------------------------------------------------------------
// Einsum: A_io[b][n][hh] = sum_k m[b][n][io*2048+k] * S[k][hh],
//   S[e*512+n'][hh] = YpT[b][io*512+e*128+hh][n'].
// Grid (8, 32); block 64n x 128h, wave 32n x 64h. m split in flight.
// ---------------------------------------------------------------------------
__global__ __launch_bounds__(256) void msg_mfma(const float* __restrict__ m,
        const _Float16* __restrict__ YpTh, const _Float16* __restrict__ YpTl,
        _Float16* __restrict__ AinH, _Float16* __restrict__ AinL,
        _Float16* __restrict__ AoutH, _Float16* __restrict__ AoutL) {
    const int tid = threadIdx.x;
    const int n0 = blockIdx.x * 64;
    const int bz = blockIdx.y;
    const int b = bz >> 1, io = bz & 1;
    const int w = tid >> 6, l = tid & 63;
    const int lm = l & 15, q = l >> 4;
    const int wr = (w & 1) * 32, wc = (w >> 1) * 64;
    const float* Ma = m + (size_t)(b * 512 + n0 + wr + lm) * 4096 + io * 2048 + q * 8;
    const float* Mb = Ma + (size_t)16 * 4096;
    const size_t yoff = ((size_t)(b * 1024) + io * 512 + wc + lm) * 512 + q * 8;
    f32x4 zero = {0.f, 0.f, 0.f, 0.f};
    f32x4 acc[2][4];
    #pragma unroll
    for (int i = 0; i < 2; i++)
        #pragma unroll
        for (int j = 0; j < 4; j++) acc[i][j] = zero;
    for (int kc = 0; kc < 2048; kc += 32) {
        const int e = kc >> 9;
        const int nb = kc & 511;
        f16x8 a0h, a0l, a1h, a1l;
        split8(Ma + kc, a0h, a0l);
        split8(Mb + kc, a1h, a1l);
        const size_t yk = yoff + (size_t)(e * 128) * 512 + nb;
        #pragma unroll
        for (int ct = 0; ct < 4; ct++) {
            f16x8 bh = *(const f16x8*)(YpTh + yk + (size_t)(ct * 16) * 512);
            f16x8 bl = *(const f16x8*)(YpTl + yk + (size_t)(ct * 16) * 512);
            acc[0][ct] = MFMA(a0h, bh, acc[0][ct]);
            acc[0][ct] = MFMA(a0h, bl, acc[0][ct]);
            acc[0][ct] = MFMA(a0l, bh, acc[0][ct]);
            acc[1][ct] = MFMA(a1h, bh, acc[1][ct]);
            acc[1][ct] = MFMA(a1h, bl, acc[1][ct]);
            acc[1][ct] = MFMA(a1l, bh, acc[1][ct]);
        }
    }
    _Float16* Ah = (io ? AoutH : AinH) + (size_t)(b * 512 + n0) * 128;
    _Float16* Al = (io ? AoutL : AinL) + (size_t)(b * 512 + n0) * 128;
    #pragma unroll
    for (int rg = 0; rg < 2; rg++)
        #pragma unroll
        for (int ct = 0; ct < 4; ct++)
            #pragma unroll
            for (int rr = 0; rr < 4; rr++) {
                size_t d = (size_t)(wr + rg * 16 + q * 4 + rr) * 128 + wc + ct * 16 + lm;
                split1(acc[rg][ct][rr], Ah + d, Al + d);
            }
}

// ---------------------------------------------------------------------------
// Gate GEMM 1: ZRT(8192x384) fp32 = [Ain|Aout|h] @ Wzrt^T, split operands.
// Grid (128, 3); block 64r x 128c, wave 32r x 64c.
// ---------------------------------------------------------------------------
__global__ __launch_bounds__(256) void gate_gemm1(
        const _Float16* __restrict__ AinH, const _Float16* __restrict__ AinL,
        const _Float16* __restrict__ AoutH, const _Float16* __restrict__ AoutL,
        const _Float16* __restrict__ hHi, const _Float16* __restrict__ hLo,
        const _Float16* __restrict__ WzrtH, const _Float16* __restrict__ WzrtL,
        float* __restrict__ ZRT) {
    const int tid = threadIdx.x;
    const int row0 = blockIdx.x * 64;
    const int c0 = blockIdx.y * 128;
    const int w = tid >> 6, l = tid & 63;
    const int lm = l & 15, q = l >> 4;
    const int wr = (w & 1) * 32, wc = (w >> 1) * 64;
    const size_t rA0 = (size_t)(row0 + wr + lm) * 128 + q * 8;
    const size_t rA1 = rA0 + 16 * 128;
    f32x4 zero = {0.f, 0.f, 0.f, 0.f};
    f32x4 acc[2][4];
    #pragma unroll
    for (int i = 0; i < 2; i++)
        #pragma unroll
        for (int j = 0; j < 4; j++) acc[i][j] = zero;
    const size_t woff = (size_t)(c0 + wc + lm) * 384 + q * 8;
    #pragma unroll
    for (int ph = 0; ph < 3; ph++) {
        const _Float16* Xh = (ph == 0) ? AinH : (ph == 1) ? AoutH : hHi;
        const _Float16* Xl = (ph == 0) ? AinL : (ph == 1) ? AoutL : hLo;
        #pragma unroll
        for (int ki = 0; ki < 4; ki++) {
            const int kc = ki * 32;
            f16x8 a0h = *(const f16x8*)(Xh + rA0 + kc);
            f16x8 a0l = *(const f16x8*)(Xl + rA0 + kc);
            f16x8 a1h = *(const f16x8*)(Xh + rA1 + kc);
            f16x8 a1l = *(const f16x8*)(Xl + rA1 + kc);
            const int kg = ph * 128 + kc;
            #pragma unroll
            for (int ct = 0; ct < 4; ct++) {
                f16x8 bh = *(const f16x8*)(WzrtH + woff + (size_t)(ct * 16) * 384 + kg);
                f16x8 bl = *(const f16x8*)(WzrtL + woff + (size_t)(ct * 16) * 384 + kg);
                acc[0][ct] = MFMA(a0h, bh, acc[0][ct]);
                acc[0][ct] = MFMA(a0h, bl, acc[0][ct]);
                acc[0][ct] = MFMA(a0l, bh, acc[0][ct]);
                acc[1][ct] = MFMA(a1h, bh, acc[1][ct]);
                acc[1][ct] = MFMA(a1h, bl, acc[1][ct]);
                acc[1][ct] = MFMA(a1l, bh, acc[1][ct]);
            }
        }
    }
    #pragma unroll
    for (int rg = 0; rg < 2; rg++)
        #pragma unroll
        for (int ct = 0; ct < 4; ct++)
            #pragma unroll
            for (int rr = 0; rr < 4; rr++)
                ZRT[(size_t)(row0 + wr + rg * 16 + q * 4 + rr) * 384 + c0 + wc + ct * 16 + lm] =
                    acc[rg][ct][rr];
}

// ---------------------------------------------------------------------------
// Gate elementwise: r = sigma(rp + b_r); RH = split(r * h).
// ---------------------------------------------------------------------------
__global__ __launch_bounds__(256) void gate_elem(const float* __restrict__ ZRT,
        const float* __restrict__ hcur, const float* __restrict__ b_r,
        _Float16* __restrict__ RHh, _Float16* __restrict__ RHl) {
    int idx = blockIdx.x * 256 + threadIdx.x;
    int row = idx >> 7, c = idx & 127;
    float rp = ZRT[(size_t)row * 384 + 128 + c] + b_r[c];
    float r = 1.0f / (1.0f + expf(-rp));
    split1(r * hcur[idx], RHh + idx, RHl + idx);
}

// ---------------------------------------------------------------------------
// Gate GEMM 2 + GRU epilogue: t2 = RH @ Wt1^T;
// z = sigma(zp + b_z); h' = (1-z)h + z*tanh(t2 + tp + b_t); write fp32 + split.
// Grid 256; block 32r x 128c, wave 16r x 64c.
// ---------------------------------------------------------------------------
__global__ __launch_bounds__(256) void gate_gemm2(
        const _Float16* __restrict__ RHh, const _Float16* __restrict__ RHl,
        const _Float16* __restrict__ Wt1h, const _Float16* __restrict__ Wt1l,
        const float* __restrict__ ZRT, const float* __restrict__ hcur,
        const float* __restrict__ b_z, const float* __restrict__ b_t,
        float* __restrict__ hnF, _Float16* __restrict__ hnH, _Float16* __restrict__ hnL) {
    const int tid = threadIdx.x;
    const int row0 = blockIdx.x * 32;
    const int w = tid >> 6, l = tid & 63;
    const int lm = l & 15, q = l >> 4;
    const int wr = (w & 1) * 16, wc = (w >> 1) * 64;
    f32x4 zero = {0.f, 0.f, 0.f, 0.f};
    f32x4 acc[4] = {zero, zero, zero, zero};
    const size_t aoff = (size_t)(row0 + wr + lm) * 128 + q * 8;
    const size_t woff = (size_t)(wc + lm) * 128 + q * 8;
    #pragma unroll
    for (int ki = 0; ki < 4; ki++) {
        const int kc = ki * 32;
        f16x8 ah = *(const f16x8*)(RHh + aoff + kc);
        f16x8 al = *(const f16x8*)(RHl + aoff + kc);
        #pragma unroll
        for (int ct = 0; ct < 4; ct++) {
            f16x8 bh = *(const f16x8*)(Wt1h + woff + (size_t)(ct * 16) * 128 + kc);
            f16x8 bl = *(const f16x8*)(Wt1l + woff + (size_t)(ct * 16) * 128 + kc);
            acc[ct] = MFMA(ah, bh, acc[ct]);
            acc[ct] = MFMA(ah, bl, acc[ct]);
            acc[ct] = MFMA(al, bh, acc[ct]);
        }
    }
    #pragma unroll
    for (int ct = 0; ct < 4; ct++)
        #pragma unroll
        for (int rr = 0; rr < 4; rr++) {
            int grow = row0 + wr + q * 4 + rr;
            int col = wc + ct * 16 + lm;
            float tp = acc[ct][rr] + ZRT[(size_t)grow * 384 + 256 + col] + b_t[col];
            float hhat = tanhf(tp);
            float zp = ZRT[(size_t)grow * 384 + col] + b_z[col];
            float z = 1.0f / (1.0f + expf(-zp));
            float hv = hcur[(size_t)grow * 128 + col];
            float hn = (1.0f - z) * hv + z * hhat;
            size_t d = (size_t)grow * 128 + col;
            hnF[d] = hn;
            split1(hn, hnH + d, hnL + d);
        }
}

// ---------------------------------------------------------------------------
// Readout: feat = tanh([h, a] @ W1 + b1); out = feat@W2 + b2 (fp32 vector).
// ---------------------------------------------------------------------------
__global__ __launch_bounds__(128) void out_kernel(
        const float* __restrict__ hfin, const float* __restrict__ a,
        const float* __restrict__ W1, const float* __restrict__ b1,
        const float* __restrict__ W2, const float* __restrict__ b2,
        float* __restrict__ out) {
    __shared__ float hrow[129];
    __shared__ float red[2];
    const int tid = threadIdx.x;
    const int grow = blockIdx.x;
    hrow[tid] = hfin[(size_t)grow * HH + tid];
    if (tid == 0) hrow[128] = a[grow];
    __syncthreads();
    float acc = b1[tid];
    for (int k = 0; k < 129; k++) acc += hrow[k] * W1[k * HH + tid];
    float feat = tanhf(acc);
    float p = feat * W2[tid];
    #pragma unroll
    for (int off = 32; off > 0; off >>= 1) p += __shfl_down(p, off, 64);
    if ((tid & 63) == 0) red[tid >> 6] = p;
    __syncthreads();
    if (tid == 0) out[grow] = red[0] + red[1] + b2[0];
}

// ---------------------------------------------------------------------------
extern "C" void kernel_launch(void* const* d_in, const int* in_sizes, int n_in,
                              void* d_out, int out_size, void* d_ws, size_t ws_size,
                              hipStream_t stream) {
    const float* x    = (const float*)d_in[0];
    const float* a    = (const float*)d_in[1];
    const float* m    = (const float*)d_in[2];
    const float* W_in = (const float*)d_in[3];
    const float* b_in = (const float*)d_in[4];
    const float* W_out= (const float*)d_in[5];
    const float* b_out= (const float*)d_in[6];
    const float* W_z  = (const float*)d_in[7];
    const float* b_z  = (const float*)d_in[8];
    const float* W_r  = (const float*)d_in[9];
    const float* b_r  = (const float*)d_in[10];
    const float* W_t  = (const float*)d_in[11];
    const float* b_t  = (const float*)d_in[12];
    const float* W1   = (const float*)d_in[13];
    const float* b1   = (const float*)d_in[14];
    const float* W2   = (const float*)d_in[15];
    const float* b2   = (const float*)d_in[16];
    float* out = (float*)d_out;

    char* p = (char*)d_ws;
    _Float16* WpTh  = (_Float16*)p; p += 262144;
    _Float16* WpTl  = (_Float16*)p; p += 262144;
    float*    bp    = (float*)p;    p += 4096;
    _Float16* WzrtH = (_Float16*)p; p += 294912;
    _Float16* WzrtL = (_Float16*)p; p += 294912;
    _Float16* Wt1h  = (_Float16*)p; p += 32768;
    _Float16* Wt1l  = (_Float16*)p; p += 32768;
    _Float16* YpTh  = (_Float16*)p; p += 16777216;
    _Float16* YpTl  = (_Float16*)p; p += 16777216;
    _Float16* AinH  = (_Float16*)p; p += 2097152;
    _Float16* AinL  = (_Float16*)p; p += 2097152;
    _Float16* AoutH = (_Float16*)p; p += 2097152;
    _Float16* AoutL = (_Float16*)p; p += 2097152;
    _Float16* RHh   = (_Float16*)p; p += 2097152;
    _Float16* RHl   = (_Float16*)p; p += 2097152;
    float*    ZRT   = (float*)p;    p += 12582912;
    float*    hA    = (float*)p;    p += 4194304;
    float*    hB    = (float*)p;    p += 4194304;
    _Float16* hHiA  = (_Float16*)p; p += 2097152;
    _Float16* hLoA  = (_Float16*)p; p += 2097152;
    _Float16* hHiB  = (_Float16*)p; p += 2097152;
    _Float16* hLoB  = (_Float16*)p; p += 2097152;   // total ~76.7 MB

    prep_kernel<<<5248, 256, 0, stream>>>(x, W_in, b_in, W_out, b_out, W_z, W_r, W_t,
                                          WpTh, WpTl, bp, WzrtH, WzrtL, Wt1h, Wt1l,
                                          hHiA, hLoA);

    const float* curF = x;
    const _Float16 *curH = hHiA, *curL = hLoA;
    for (int s = 0; s < NSTEPS; s++) {
        float*    nF = (s & 1) ? hB : hA;
        _Float16* nH = (s & 1) ? hHiA : hHiB;
        _Float16* nL = (s & 1) ? hLoA : hLoB;
        xw_mfma<<<dim3(16, 4, 16), 256, 0, stream>>>(curH, curL, WpTh, WpTl, bp, YpTh, YpTl);
        msg_mfma<<<dim3(8, 32), 256, 0, stream>>>(m, YpTh, YpTl, AinH, AinL, AoutH, AoutL);
        gate_gemm1<<<dim3(128, 3), 256, 0, stream>>>(AinH, AinL, AoutH, AoutL,
                                                     curH, curL, WzrtH, WzrtL, ZRT);
        gate_elem<<<4096, 256, 0, stream>>>(ZRT, curF, b_r, RHh, RHl);
        gate_gemm2<<<256, 256, 0, stream>>>(RHh, RHl, Wt1h, Wt1l, ZRT, curF,
                                            b_z, b_t, nF, nH, nL);
        curF = nF; curH = nH; curL = nL;
    }
    out_kernel<<<ROWS, 128, 0, stream>>>(curF, a, W1, b1, W2, b2, out);
}

// Round 4
// 1138.334 us; speedup vs baseline: 1.3387x; 1.3387x over previous
//
#include <hip/hip_runtime.h>
#include <math.h>

#define BB 16
#define NN 512
#define HH 128
#define EE 4
#define NSTEPS 5
#define ROWS (BB*NN)      // 8192
#define KDIM (NN*EE)      // 2048

typedef _Float16 f16x8 __attribute__((ext_vector_type(8)));
typedef float f32x4 __attribute__((ext_vector_type(4)));

#define MFMA(a,b,c) __builtin_amdgcn_mfma_f32_16x16x32_f16(a, b, c, 0, 0, 0)

__device__ inline void split8(const float* __restrict__ p, f16x8& hi, f16x8& lo) {
    const float4 u = *(const float4*)p;
    const float4 v = *(const float4*)(p + 4);
    float f[8] = {u.x, u.y, u.z, u.w, v.x, v.y, v.z, v.w};
    #pragma unroll
    for (int i = 0; i < 8; i++) {
        _Float16 h = (_Float16)f[i];
        hi[i] = h;
        lo[i] = (_Float16)(f[i] - (float)h);
    }
}

__device__ inline void split8v(float4 u, float4 v, f16x8& hi, f16x8& lo) {
    float f[8] = {u.x, u.y, u.z, u.w, v.x, v.y, v.z, v.w};
    #pragma unroll
    for (int i = 0; i < 8; i++) {
        _Float16 h = (_Float16)f[i];
        hi[i] = h;
        lo[i] = (_Float16)(f[i] - (float)h);
    }
}

__device__ inline void split1(float v, _Float16* __restrict__ hp, _Float16* __restrict__ lp) {
    _Float16 h = (_Float16)v;
    *hp = h;
    *lp = (_Float16)(v - (float)h);
}

// ---------------------------------------------------------------------------
// Prep: split-fp16 transposed weights + split of initial h = x.
// ---------------------------------------------------------------------------
__global__ void prep_kernel(const float* __restrict__ x,
                            const float* __restrict__ W_in, const float* __restrict__ b_in,
                            const float* __restrict__ W_out, const float* __restrict__ b_out,
                            const float* __restrict__ W_z, const float* __restrict__ W_r,
                            const float* __restrict__ W_t,
                            _Float16* __restrict__ WpTh, _Float16* __restrict__ WpTl,
                            float* __restrict__ bp,
                            _Float16* __restrict__ WzrtH, _Float16* __restrict__ WzrtL,
                            _Float16* __restrict__ Wt1h, _Float16* __restrict__ Wt1l,
                            _Float16* __restrict__ hHi, _Float16* __restrict__ hLo) {
    int idx = blockIdx.x * 256 + threadIdx.x;
    if (idx < 131072) {                                  // WpT
        int c = idx >> 7, k = idx & 127;
        int io = c >> 9, cc = c & 511, e = cc >> 7, hh = cc & 127;
        const float* W = io ? W_out : W_in;
        split1(W[k * 512 + hh * 4 + e], WpTh + idx, WpTl + idx);
        if (k == 0) bp[c] = (io ? b_out : b_in)[hh * 4 + e];
    } else if (idx < 131072 + 147456) {                  // Wzrt
        int j = idx - 131072;
        int c = j / 384, k = j - c * 384;
        float v;
        if (c < 128)      v = W_z[k * 128 + c];
        else if (c < 256) v = W_r[k * 128 + (c - 128)];
        else              v = (k < 256) ? W_t[k * 128 + (c - 256)] : 0.0f;
        split1(v, WzrtH + j, WzrtL + j);
    } else if (idx < 131072 + 147456 + 16384) {          // Wt1
        int j = idx - 131072 - 147456;
        int c = j >> 7, k = j & 127;
        split1(W_t[(256 + k) * 128 + c], Wt1h + j, Wt1l + j);
    } else if (idx < 131072 + 147456 + 16384 + 1048576) { // split x -> h hi/lo
        int j = idx - 131072 - 147456 - 16384;
        split1(x[j], hHi + j, hLo + j);
    }
}

// ---------------------------------------------------------------------------
// YpT[b][c][n'] = sum_k WpT[c][k] * h[b*512+n'][k] + bp[c], split-fp16 out.
// Grid (16,4,16); block 64c x 128n, 4 waves (wave 32c x 64n).
// ---------------------------------------------------------------------------
__global__ __launch_bounds__(256) void xw_mfma(
        const _Float16* __restrict__ hHi, const _Float16* __restrict__ hLo,
        const _Float16* __restrict__ WpTh, const _Float16* __restrict__ WpTl,
        const float* __restrict__ bp,
        _Float16* __restrict__ YpTh, _Float16* __restrict__ YpTl) {
    const int tid = threadIdx.x;
    const int c0 = blockIdx.x * 64;
    const int n0 = blockIdx.y * 128;
    const int b  = blockIdx.z;
    const int w = tid >> 6, l = tid & 63;
    const int lm = l & 15, q = l >> 4;
    const int wr = (w & 1) * 32, wc = (w >> 1) * 64;
    f32x4 zero = {0.f, 0.f, 0.f, 0.f};
    f32x4 acc[2][4];
    #pragma unroll
    for (int i = 0; i < 2; i++)
        #pragma unroll
        for (int j = 0; j < 4; j++) acc[i][j] = zero;
    const size_t aoff = (size_t)(c0 + wr + lm) * 128 + q * 8;
    const size_t boff = (size_t)(b * 512 + n0 + wc + lm) * 128 + q * 8;
    #pragma unroll
    for (int ki = 0; ki < 4; ki++) {
        const int kc = ki * 32;
        f16x8 a0h = *(const f16x8*)(WpTh + aoff + kc);
        f16x8 a0l = *(const f16x8*)(WpTl + aoff + kc);
        f16x8 a1h = *(const f16x8*)(WpTh + aoff + 16 * 128 + kc);
        f16x8 a1l = *(const f16x8*)(WpTl + aoff + 16 * 128 + kc);
        #pragma unroll
        for (int ct = 0; ct < 4; ct++) {
            f16x8 bh = *(const f16x8*)(hHi + boff + (size_t)(ct * 16) * 128 + kc);
            f16x8 bl = *(const f16x8*)(hLo + boff + (size_t)(ct * 16) * 128 + kc);
            acc[0][ct] = MFMA(a0h, bh, acc[0][ct]);
            acc[0][ct] = MFMA(a0h, bl, acc[0][ct]);
            acc[0][ct] = MFMA(a0l, bh, acc[0][ct]);
            acc[1][ct] = MFMA(a1h, bh, acc[1][ct]);
            acc[1][ct] = MFMA(a1h, bl, acc[1][ct]);
            acc[1][ct] = MFMA(a1l, bh, acc[1][ct]);
        }
    }
    #pragma unroll
    for (int rg = 0; rg < 2; rg++)
        #pragma unroll
        for (int rr = 0; rr < 4; rr++) {
            int c = c0 + wr + rg * 16 + q * 4 + rr;
            float bias = bp[c];
            size_t d = ((size_t)b * 1024 + c) * 512 + n0 + wc + lm;
            #pragma unroll
            for (int ct = 0; ct < 4; ct++) {
                float v = acc[rg][ct][rr] + bias;
                split1(v, YpTh + d + ct * 16, YpTl + d + ct * 16);
            }
        }
}

// ---------------------------------------------------------------------------
// Einsum, K-split x4, register double-buffered.
// Apart[kz][b*2+io][n][hh] (fp32) = partial over k in [kz*512, kz*512+512).
// Grid (8 nTiles, 32 b*io, 4 kz); block 64n x 128h, wave 32n x 64h.
// Within a slice e = kz is constant -> all addresses affine in i.
// ---------------------------------------------------------------------------
__global__ __launch_bounds__(256) void msg_mfma(const float* __restrict__ m,
        const _Float16* __restrict__ YpTh, const _Float16* __restrict__ YpTl,
        float* __restrict__ Apart) {
    const int tid = threadIdx.x;
    const int n0 = blockIdx.x * 64;
    const int biz = blockIdx.y;
    const int kz = blockIdx.z;
    const int b = biz >> 1, io = biz & 1;
    const int w = tid >> 6, l = tid & 63;
    const int lm = l & 15, q = l >> 4;
    const int wr = (w & 1) * 32, wc = (w >> 1) * 64;
    const float* Ma = m + (size_t)(b * 512 + n0 + wr + lm) * 4096 + io * 2048 + kz * 512 + q * 8;
    const float* Mb = Ma + (size_t)16 * 4096;
    const size_t yrow = (size_t)(b * 1024 + io * 512 + kz * 128 + wc + lm) * 512 + q * 8;
    const _Float16* Ybh = YpTh + yrow;
    const _Float16* Ybl = YpTl + yrow;

    f32x4 zero = {0.f, 0.f, 0.f, 0.f};
    f32x4 acc[2][4];
    #pragma unroll
    for (int i = 0; i < 2; i++)
        #pragma unroll
        for (int j = 0; j < 4; j++) acc[i][j] = zero;

    float4 ma[2][4];      // [buf][row0_lo, row0_hi, row1_lo, row1_hi]
    f16x8 ybh[2][4], ybl[2][4];

    #define LOADCHUNK(buf, i)  do {                                            \
        ma[buf][0] = *(const float4*)(Ma + (i) * 32);                          \
        ma[buf][1] = *(const float4*)(Ma + (i) * 32 + 4);                      \
        ma[buf][2] = *(const float4*)(Mb + (i) * 32);                          \
        ma[buf][3] = *(const float4*)(Mb + (i) * 32 + 4);                      \
        _Pragma("unroll")                                                      \
        for (int ct = 0; ct < 4; ct++) {                                       \
            ybh[buf][ct] = *(const f16x8*)(Ybh + (size_t)(ct * 16) * 512 + (i) * 32); \
            ybl[buf][ct] = *(const f16x8*)(Ybl + (size_t)(ct * 16) * 512 + (i) * 32); \
        }                                                                      \
    } while (0)

    LOADCHUNK(0, 0);
    #pragma unroll
    for (int i = 0; i < 16; i++) {
        const int cur = i & 1;
        if (i < 15) LOADCHUNK(cur ^ 1, i + 1);
        f16x8 a0h, a0l, a1h, a1l;
        split8v(ma[cur][0], ma[cur][1], a0h, a0l);
        split8v(ma[cur][2], ma[cur][3], a1h, a1l);
        #pragma unroll
        for (int ct = 0; ct < 4; ct++) {
            f16x8 bh = ybh[cur][ct];
            f16x8 bl = ybl[cur][ct];
            acc[0][ct] = MFMA(a0h, bh, acc[0][ct]);
            acc[0][ct] = MFMA(a0h, bl, acc[0][ct]);
            acc[0][ct] = MFMA(a0l, bh, acc[0][ct]);
            acc[1][ct] = MFMA(a1h, bh, acc[1][ct]);
            acc[1][ct] = MFMA(a1h, bl, acc[1][ct]);
            acc[1][ct] = MFMA(a1l, bh, acc[1][ct]);
        }
    }
    #undef LOADCHUNK

    float* Ap = Apart + (((size_t)(kz * 32 + biz) * 512) + n0 + wr) * 128 + wc;
    #pragma unroll
    for (int rg = 0; rg < 2; rg++)
        #pragma unroll
        for (int ct = 0; ct < 4; ct++)
            #pragma unroll
            for (int rr = 0; rr < 4; rr++)
                Ap[(size_t)(rg * 16 + q * 4 + rr) * 128 + ct * 16 + lm] = acc[rg][ct][rr];
}

// ---------------------------------------------------------------------------
// Reduce 4 K-slices and split to fp16 hi/lo Ain/Aout. float4 per thread.
// Grid 2048 x 256.
// ---------------------------------------------------------------------------
__global__ __launch_bounds__(256) void msg_reduce(const float* __restrict__ Apart,
        _Float16* __restrict__ AinH, _Float16* __restrict__ AinL,
        _Float16* __restrict__ AoutH, _Float16* __restrict__ AoutL) {
    const size_t SL = (size_t)32 * 512 * 128;   // 2,097,152
    size_t idx = ((size_t)blockIdx.x * 256 + threadIdx.x) * 4;
    float4 v0 = *(const float4*)(Apart + idx);
    float4 v1 = *(const float4*)(Apart + idx + SL);
    float4 v2 = *(const float4*)(Apart + idx + 2 * SL);
    float4 v3 = *(const float4*)(Apart + idx + 3 * SL);
    float s[4] = {v0.x + v1.x + v2.x + v3.x, v0.y + v1.y + v2.y + v3.y,
                  v0.z + v1.z + v2.z + v3.z, v0.w + v1.w + v2.w + v3.w};
    int biz = (int)(idx >> 16);
    int rem = (int)(idx & 65535);
    int b = biz >> 1, io = biz & 1;
    size_t d = ((size_t)b << 16) + rem;
    _Float16* Ah = (io ? AoutH : AinH) + d;
    _Float16* Al = (io ? AoutL : AinL) + d;
    #pragma unroll
    for (int j = 0; j < 4; j++) split1(s[j], Ah + j, Al + j);
}

// ---------------------------------------------------------------------------
// Gate GEMM 1: ZRT(8192x384) fp32 = [Ain|Aout|h] @ Wzrt^T, split operands.
// Grid (128, 3); block 64r x 128c, wave 32r x 64c.
// ---------------------------------------------------------------------------
__global__ __launch_bounds__(256) void gate_gemm1(
        const _Float16* __restrict__ AinH, const _Float16* __restrict__ AinL,
        const _Float16* __restrict__ AoutH, const _Float16* __restrict__ AoutL,
        const _Float16* __restrict__ hHi, const _Float16* __restrict__ hLo,
        const _Float16* __restrict__ WzrtH, const _Float16* __restrict__ WzrtL,
        float* __restrict__ ZRT) {
    const int tid = threadIdx.x;
    const int row0 = blockIdx.x * 64;
    const int c0 = blockIdx.y * 128;
    const int w = tid >> 6, l = tid & 63;
    const int lm = l & 15, q = l >> 4;
    const int wr = (w & 1) * 32, wc = (w >> 1) * 64;
    const size_t rA0 = (size_t)(row0 + wr + lm) * 128 + q * 8;
    const size_t rA1 = rA0 + 16 * 128;
    f32x4 zero = {0.f, 0.f, 0.f, 0.f};
    f32x4 acc[2][4];
    #pragma unroll
    for (int i = 0; i < 2; i++)
        #pragma unroll
        for (int j = 0; j < 4; j++) acc[i][j] = zero;
    const size_t woff = (size_t)(c0 + wc + lm) * 384 + q * 8;
    #pragma unroll
    for (int ph = 0; ph < 3; ph++) {
        const _Float16* Xh = (ph == 0) ? AinH : (ph == 1) ? AoutH : hHi;
        const _Float16* Xl = (ph == 0) ? AinL : (ph == 1) ? AoutL : hLo;
        #pragma unroll
        for (int ki = 0; ki < 4; ki++) {
            const int kc = ki * 32;
            f16x8 a0h = *(const f16x8*)(Xh + rA0 + kc);
            f16x8 a0l = *(const f16x8*)(Xl + rA0 + kc);
            f16x8 a1h = *(const f16x8*)(Xh + rA1 + kc);
            f16x8 a1l = *(const f16x8*)(Xl + rA1 + kc);
            const int kg = ph * 128 + kc;
            #pragma unroll
            for (int ct = 0; ct < 4; ct++) {
                f16x8 bh = *(const f16x8*)(WzrtH + woff + (size_t)(ct * 16) * 384 + kg);
                f16x8 bl = *(const f16x8*)(WzrtL + woff + (size_t)(ct * 16) * 384 + kg);
                acc[0][ct] = MFMA(a0h, bh, acc[0][ct]);
                acc[0][ct] = MFMA(a0h, bl, acc[0][ct]);
                acc[0][ct] = MFMA(a0l, bh, acc[0][ct]);
                acc[1][ct] = MFMA(a1h, bh, acc[1][ct]);
                acc[1][ct] = MFMA(a1h, bl, acc[1][ct]);
                acc[1][ct] = MFMA(a1l, bh, acc[1][ct]);
            }
        }
    }
    #pragma unroll
    for (int rg = 0; rg < 2; rg++)
        #pragma unroll
        for (int ct = 0; ct < 4; ct++)
            #pragma unroll
            for (int rr = 0; rr < 4; rr++)
                ZRT[(size_t)(row0 + wr + rg * 16 + q * 4 + rr) * 384 + c0 + wc + ct * 16 + lm] =
                    acc[rg][ct][rr];
}

// ---------------------------------------------------------------------------
// Gate elementwise: r = sigma(rp + b_r); RH = split(r * h).
// ---------------------------------------------------------------------------
__global__ __launch_bounds__(256) void gate_elem(const float* __restrict__ ZRT,
        const float* __restrict__ hcur, const float* __restrict__ b_r,
        _Float16* __restrict__ RHh, _Float16* __restrict__ RHl) {
    int idx = blockIdx.x * 256 + threadIdx.x;
    int row = idx >> 7, c = idx & 127;
    float rp = ZRT[(size_t)row * 384 + 128 + c] + b_r[c];
    float r = 1.0f / (1.0f + expf(-rp));
    split1(r * hcur[idx], RHh + idx, RHl + idx);
}

// ---------------------------------------------------------------------------
// Gate GEMM 2 + GRU epilogue.
// ---------------------------------------------------------------------------
__global__ __launch_bounds__(256) void gate_gemm2(
        const _Float16* __restrict__ RHh, const _Float16* __restrict__ RHl,
        const _Float16* __restrict__ Wt1h, const _Float16* __restrict__ Wt1l,
        const float* __restrict__ ZRT, const float* __restrict__ hcur,
        const float* __restrict__ b_z, const float* __restrict__ b_t,
        float* __restrict__ hnF, _Float16* __restrict__ hnH, _Float16* __restrict__ hnL) {
    const int tid = threadIdx.x;
    const int row0 = blockIdx.x * 32;
    const int w = tid >> 6, l = tid & 63;
    const int lm = l & 15, q = l >> 4;
    const int wr = (w & 1) * 16, wc = (w >> 1) * 64;
    f32x4 zero = {0.f, 0.f, 0.f, 0.f};
    f32x4 acc[4] = {zero, zero, zero, zero};
    const size_t aoff = (size_t)(row0 + wr + lm) * 128 + q * 8;
    const size_t woff = (size_t)(wc + lm) * 128 + q * 8;
    #pragma unroll
    for (int ki = 0; ki < 4; ki++) {
        const int kc = ki * 32;
        f16x8 ah = *(const f16x8*)(RHh + aoff + kc);
        f16x8 al = *(const f16x8*)(RHl + aoff + kc);
        #pragma unroll
        for (int ct = 0; ct < 4; ct++) {
            f16x8 bh = *(const f16x8*)(Wt1h + woff + (size_t)(ct * 16) * 128 + kc);
            f16x8 bl = *(const f16x8*)(Wt1l + woff + (size_t)(ct * 16) * 128 + kc);
            acc[ct] = MFMA(ah, bh, acc[ct]);
            acc[ct] = MFMA(ah, bl, acc[ct]);
            acc[ct] = MFMA(al, bh, acc[ct]);
        }
    }
    #pragma unroll
    for (int ct = 0; ct < 4; ct++)
        #pragma unroll
        for (int rr = 0; rr < 4; rr++) {
            int grow = row0 + wr + q * 4 + rr;
            int col = wc + ct * 16 + lm;
            float tp = acc[ct][rr] + ZRT[(size_t)grow * 384 + 256 + col] + b_t[col];
            float hhat = tanhf(tp);
            float zp = ZRT[(size_t)grow * 384 + col] + b_z[col];
            float z = 1.0f / (1.0f + expf(-zp));
            float hv = hcur[(size_t)grow * 128 + col];
            float hn = (1.0f - z) * hv + z * hhat;
            size_t d = (size_t)grow * 128 + col;
            hnF[d] = hn;
            split1(hn, hnH + d, hnL + d);
        }
}

// ---------------------------------------------------------------------------
// Readout: feat = tanh([h, a] @ W1 + b1); out = feat@W2 + b2 (fp32 vector).
// ---------------------------------------------------------------------------
__global__ __launch_bounds__(128) void out_kernel(
        const float* __restrict__ hfin, const float* __restrict__ a,
        const float* __restrict__ W1, const float* __restrict__ b1,
        const float* __restrict__ W2, const float* __restrict__ b2,
        float* __restrict__ out) {
    __shared__ float hrow[129];
    __shared__ float red[2];
    const int tid = threadIdx.x;
    const int grow = blockIdx.x;
    hrow[tid] = hfin[(size_t)grow * HH + tid];
    if (tid == 0) hrow[128] = a[grow];
    __syncthreads();
    float acc = b1[tid];
    for (int k = 0; k < 129; k++) acc += hrow[k] * W1[k * HH + tid];
    float feat = tanhf(acc);
    float p = feat * W2[tid];
    #pragma unroll
    for (int off = 32; off > 0; off >>= 1) p += __shfl_down(p, off, 64);
    if ((tid & 63) == 0) red[tid >> 6] = p;
    __syncthreads();
    if (tid == 0) out[grow] = red[0] + red[1] + b2[0];
}

// ---------------------------------------------------------------------------
extern "C" void kernel_launch(void* const* d_in, const int* in_sizes, int n_in,
                              void* d_out, int out_size, void* d_ws, size_t ws_size,
                              hipStream_t stream) {
    const float* x    = (const float*)d_in[0];
    const float* a    = (const float*)d_in[1];
    const float* m    = (const float*)d_in[2];
    const float* W_in = (const float*)d_in[3];
    const float* b_in = (const float*)d_in[4];
    const float* W_out= (const float*)d_in[5];
    const float* b_out= (const float*)d_in[6];
    const float* W_z  = (const float*)d_in[7];
    const float* b_z  = (const float*)d_in[8];
    const float* W_r  = (const float*)d_in[9];
    const float* b_r  = (const float*)d_in[10];
    const float* W_t  = (const float*)d_in[11];
    const float* b_t  = (const float*)d_in[12];
    const float* W1   = (const float*)d_in[13];
    const float* b1   = (const float*)d_in[14];
    const float* W2   = (const float*)d_in[15];
    const float* b2   = (const float*)d_in[16];
    float* out = (float*)d_out;

    char* p = (char*)d_ws;
    _Float16* WpTh  = (_Float16*)p; p += 262144;
    _Float16* WpTl  = (_Float16*)p; p += 262144;
    float*    bp    = (float*)p;    p += 4096;
    _Float16* WzrtH = (_Float16*)p; p += 294912;
    _Float16* WzrtL = (_Float16*)p; p += 294912;
    _Float16* Wt1h  = (_Float16*)p; p += 32768;
    _Float16* Wt1l  = (_Float16*)p; p += 32768;
    _Float16* YpTh  = (_Float16*)p; p += 16777216;
    _Float16* YpTl  = (_Float16*)p; p += 16777216;
    _Float16* AinH  = (_Float16*)p; p += 2097152;
    _Float16* AinL  = (_Float16*)p; p += 2097152;
    _Float16* AoutH = (_Float16*)p; p += 2097152;
    _Float16* AoutL = (_Float16*)p; p += 2097152;
    _Float16* RHh   = (_Float16*)p; p += 2097152;
    _Float16* RHl   = (_Float16*)p; p += 2097152;
    float*    ZRT   = (float*)p;    p += 12582912;
    float*    hA    = (float*)p;    p += 4194304;
    float*    hB    = (float*)p;    p += 4194304;
    _Float16* hHiA  = (_Float16*)p; p += 2097152;
    _Float16* hLoA  = (_Float16*)p; p += 2097152;
    _Float16* hHiB  = (_Float16*)p; p += 2097152;
    _Float16* hLoB  = (_Float16*)p; p += 2097152;
    float*    Apart = (float*)p;    p += 33554432;   // total ~110.3 MB

    prep_kernel<<<5248, 256, 0, stream>>>(x, W_in, b_in, W_out, b_out, W_z, W_r, W_t,
                                          WpTh, WpTl, bp, WzrtH, WzrtL, Wt1h, Wt1l,
                                          hHiA, hLoA);

    const float* curF = x;
    const _Float16 *curH = hHiA, *curL = hLoA;
    for (int s = 0; s < NSTEPS; s++) {
        float*    nF = (s & 1) ? hB : hA;
        _Float16* nH = (s & 1) ? hHiA : hHiB;
        _Float16* nL = (s & 1) ? hLoA : hLoB;
        xw_mfma<<<dim3(16, 4, 16), 256, 0, stream>>>(curH, curL, WpTh, WpTl, bp, YpTh, YpTl);
        msg_mfma<<<dim3(8, 32, 4), 256, 0, stream>>>(m, YpTh, YpTl, Apart);
        msg_reduce<<<2048, 256, 0, stream>>>(Apart, AinH, AinL, AoutH, AoutL);
        gate_gemm1<<<dim3(128, 3), 256, 0, stream>>>(AinH, AinL, AoutH, AoutL,
                                                     curH, curL, WzrtH, WzrtL, ZRT);
        gate_elem<<<4096, 256, 0, stream>>>(ZRT, curF, b_r, RHh, RHl);
        gate_gemm2<<<256, 256, 0, stream>>>(RHh, RHl, Wt1h, Wt1l, ZRT, curF,
                                            b_z, b_t, nF, nH, nL);
        curF = nF; curH = nH; curL = nL;
    }
    out_kernel<<<ROWS, 128, 0, stream>>>(curF, a, W1, b1, W2, b2, out);
}